// Round 1
// baseline (1575.364 us; speedup 1.0000x reference)
//
#include <hip/hip_runtime.h>

#define BB 32
#define NN 256
#define EE 300
#define HH 256
#define KK 8
#define MARGINF 0.2f

// ---------------------------------------------------------------------------
// proj: A[b,h,n] = bias[h] + sum_e X[b,n,e] * W[h,e]     (stored [B,H,N])
// grid (4 n-tiles, 4 h-tiles, B), block 256. 64x64 tile, 4x4 per thread.
// ---------------------------------------------------------------------------
__global__ __launch_bounds__(256) void proj_kernel(
    const float* __restrict__ X, const float* __restrict__ W,
    const float* __restrict__ bias, float* __restrict__ A)
{
  const int b  = blockIdx.z;
  const int h0 = blockIdx.y * 64;
  const int n0 = blockIdx.x * 64;
  const int tid = threadIdx.x;

  __shared__ __align__(16) float Ws[32][68];  // [e][h], pad 68 keeps rows 16B-aligned
  __shared__ __align__(16) float Xs[32][68];  // [e][n]

  const int th = tid & 15;   // h = h0 + th + 16*i
  const int tn = tid >> 4;   // n = n0 + tn*4 + j  (4 consecutive n -> float4 I/O)
  const int le = tid & 31;
  const int lr = tid >> 5;

  float acc[4][4];
#pragma unroll
  for (int i = 0; i < 4; i++)
#pragma unroll
    for (int j = 0; j < 4; j++) acc[i][j] = 0.f;

  const float* Xb = X + (size_t)b * NN * EE;

  for (int e0 = 0; e0 < EE; e0 += 32) {
    const int e = e0 + le;
    const bool ok = (e < EE);                 // E=300 tail -> zero-fill
#pragma unroll
    for (int r = 0; r < 8; r++) {
      const int row = lr + 8 * r;             // 0..63
      Ws[le][row] = ok ? W[(size_t)(h0 + row) * EE + e] : 0.f;
      Xs[le][row] = ok ? Xb[(size_t)(n0 + row) * EE + e] : 0.f;
    }
    __syncthreads();
#pragma unroll
    for (int ee = 0; ee < 32; ee++) {
      float wv[4];
#pragma unroll
      for (int i = 0; i < 4; i++) wv[i] = Ws[ee][th + 16 * i];
      const float4 xv = *(const float4*)&Xs[ee][tn * 4];
      const float xa[4] = {xv.x, xv.y, xv.z, xv.w};
#pragma unroll
      for (int i = 0; i < 4; i++)
#pragma unroll
        for (int j = 0; j < 4; j++) acc[i][j] += wv[i] * xa[j];
    }
    __syncthreads();
  }

  float* Ab = A + (size_t)b * HH * NN;
#pragma unroll
  for (int i = 0; i < 4; i++) {
    const int h = h0 + th + 16 * i;
    const float bi = bias[h];
    float4 v;
    v.x = acc[i][0] + bi; v.y = acc[i][1] + bi;
    v.z = acc[i][2] + bi; v.w = acc[i][3] + bi;
    *(float4*)&Ab[(size_t)h * NN + n0 + tn * 4] = v;
  }
}

// ---------------------------------------------------------------------------
// stats: per (which,b,k): global softmax max m and sumexp l over
// S[n,m] = sum_h (W_att[k,h]*Aa[b,h,n]) * Ac[b,h,m]   (65536 logits)
// One WG per (which,b,k), 512 WGs. S computed tile-by-tile (64x64), online m/l.
// b_att cancels in softmax -> ignored.
// ---------------------------------------------------------------------------
__global__ __launch_bounds__(256) void stats_kernel(
    const float* __restrict__ Aa, const float* __restrict__ Ap,
    const float* __restrict__ An, const float* __restrict__ Watt,
    float* __restrict__ stats)
{
  const int idx = blockIdx.x;          // which*256 + b*8 + k
  const int k = idx & 7;
  const int b = (idx >> 3) & 31;
  const int which = idx >> 8;
  const int tid = threadIdx.x;

  const float* Ab = Aa + (size_t)b * HH * NN;
  const float* Cb = (which ? An : Ap) + (size_t)b * HH * NN;
  const float* wk = Watt + (size_t)k * HH;

  __shared__ __align__(16) float As[32][68];
  __shared__ __align__(16) float Cs[32][68];
  __shared__ float red_m[256];
  __shared__ float red_l[256];

  const int tn4 = (tid & 15) * 4;
  const int tm4 = (tid >> 4) * 4;
  const int lc  = tid & 63;
  const int wid = tid >> 6;            // wave id -> uniform hh base (scalar wk load)

  float m_t = -1e30f, l_t = 0.f;

  for (int t = 0; t < 16; t++) {
    const int n0 = (t & 3) * 64, m0 = (t >> 2) * 64;
    float acc[4][4];
#pragma unroll
    for (int i = 0; i < 4; i++)
#pragma unroll
      for (int j = 0; j < 4; j++) acc[i][j] = 0.f;

    for (int h0 = 0; h0 < HH; h0 += 32) {
#pragma unroll
      for (int r = 0; r < 8; r++) {
        const int hh = wid + 4 * r;
        const float w = wk[h0 + hh];
        As[hh][lc] = w * Ab[(size_t)(h0 + hh) * NN + n0 + lc];
        Cs[hh][lc] =     Cb[(size_t)(h0 + hh) * NN + m0 + lc];
      }
      __syncthreads();
#pragma unroll
      for (int hh = 0; hh < 32; hh++) {
        const float4 a4 = *(const float4*)&As[hh][tn4];
        const float4 c4 = *(const float4*)&Cs[hh][tm4];
        const float av[4] = {a4.x, a4.y, a4.z, a4.w};
        const float cv[4] = {c4.x, c4.y, c4.z, c4.w};
#pragma unroll
        for (int i = 0; i < 4; i++)
#pragma unroll
          for (int j = 0; j < 4; j++) acc[i][j] += av[i] * cv[j];
      }
      __syncthreads();
    }
#pragma unroll
    for (int i = 0; i < 4; i++)
#pragma unroll
      for (int j = 0; j < 4; j++) {
        const float s = acc[i][j];
        if (s > m_t) { l_t = l_t * __expf(m_t - s) + 1.f; m_t = s; }
        else l_t += __expf(s - m_t);
      }
  }

  red_m[tid] = m_t; red_l[tid] = l_t;
  __syncthreads();
  for (int s2 = 128; s2 > 0; s2 >>= 1) {
    if (tid < s2) {
      const float m1 = red_m[tid], l1 = red_l[tid];
      const float m2 = red_m[tid + s2], l2 = red_l[tid + s2];
      const float mm = fmaxf(m1, m2);
      red_m[tid] = mm;
      red_l[tid] = l1 * __expf(m1 - mm) + l2 * __expf(m2 - mm);
    }
    __syncthreads();
  }
  if (tid == 0) { stats[idx * 2] = red_m[0]; stats[idx * 2 + 1] = red_l[0]; }
}

// ---------------------------------------------------------------------------
// attnout: out[which,b,k,h] = (1/l) * sum_{n,m} Aa[b,h,n]*exp(S[n,m]-m)*Ac[b,h,m]
// One WG per (which,b,k). Per 64x64 tile: recompute S (identical FMA order to
// stats -> bitwise-identical logits), exp into LDS, then thread h=tid does the
// bilinear accumulation from its Aa/Ac rows (L1-resident).
// ---------------------------------------------------------------------------
__global__ __launch_bounds__(256) void attnout_kernel(
    const float* __restrict__ Aa, const float* __restrict__ Ap,
    const float* __restrict__ An, const float* __restrict__ Watt,
    const float* __restrict__ stats, float* __restrict__ outPN)
{
  const int idx = blockIdx.x;
  const int k = idx & 7;
  const int b = (idx >> 3) & 31;
  const int which = idx >> 8;
  const int tid = threadIdx.x;

  const float* Ab = Aa + (size_t)b * HH * NN;
  const float* Cb = (which ? An : Ap) + (size_t)b * HH * NN;
  const float* wk = Watt + (size_t)k * HH;
  const float gm    = stats[idx * 2];
  const float inv_l = 1.0f / stats[idx * 2 + 1];

  __shared__ __align__(16) float As[32][68];
  __shared__ __align__(16) float Cs[32][68];
  __shared__ __align__(16) float Pt[64][68];

  const int tn4 = (tid & 15) * 4;
  const int tm4 = (tid >> 4) * 4;
  const int lc  = tid & 63;
  const int wid = tid >> 6;

  float out_h = 0.f;
  const float* ArowBase = Ab + (size_t)tid * NN;  // thread owns h = tid
  const float* CrowBase = Cb + (size_t)tid * NN;

  for (int t = 0; t < 16; t++) {
    const int n0 = (t & 3) * 64, m0 = (t >> 2) * 64;
    float acc[4][4];
#pragma unroll
    for (int i = 0; i < 4; i++)
#pragma unroll
      for (int j = 0; j < 4; j++) acc[i][j] = 0.f;

    for (int h0 = 0; h0 < HH; h0 += 32) {
#pragma unroll
      for (int r = 0; r < 8; r++) {
        const int hh = wid + 4 * r;
        const float w = wk[h0 + hh];
        As[hh][lc] = w * Ab[(size_t)(h0 + hh) * NN + n0 + lc];
        Cs[hh][lc] =     Cb[(size_t)(h0 + hh) * NN + m0 + lc];
      }
      __syncthreads();
#pragma unroll
      for (int hh = 0; hh < 32; hh++) {
        const float4 a4 = *(const float4*)&As[hh][tn4];
        const float4 c4 = *(const float4*)&Cs[hh][tm4];
        const float av[4] = {a4.x, a4.y, a4.z, a4.w};
        const float cv[4] = {c4.x, c4.y, c4.z, c4.w};
#pragma unroll
        for (int i = 0; i < 4; i++)
#pragma unroll
          for (int j = 0; j < 4; j++) acc[i][j] += av[i] * cv[j];
      }
      __syncthreads();
    }

    // P tile = exp(S - m)  (divide by l once at the end)
#pragma unroll
    for (int i = 0; i < 4; i++) {
      float4 v;
      v.x = __expf(acc[i][0] - gm); v.y = __expf(acc[i][1] - gm);
      v.z = __expf(acc[i][2] - gm); v.w = __expf(acc[i][3] - gm);
      *(float4*)&Pt[tn4 + i][tm4] = v;
    }
    __syncthreads();

    // bilinear accumulate: out_h += Aa[h,n0+n] * Pt[n][m] * Ac[h,m0+m]
    const float* Arow = ArowBase + n0;
    const float* Crow = CrowBase + m0;
#pragma unroll 1
    for (int mc = 0; mc < 4; mc++) {
      float c[16];
#pragma unroll
      for (int q = 0; q < 4; q++) {
        const float4 cc = *(const float4*)&Crow[mc * 16 + q * 4];
        c[q * 4] = cc.x; c[q * 4 + 1] = cc.y; c[q * 4 + 2] = cc.z; c[q * 4 + 3] = cc.w;
      }
      float part = 0.f;
      for (int n = 0; n < 64; n += 4) {
        const float4 a4 = *(const float4*)&Arow[n];
        const float aa[4] = {a4.x, a4.y, a4.z, a4.w};
#pragma unroll
        for (int u = 0; u < 4; u++) {
          const float* prow = &Pt[n + u][mc * 16];
          float s = 0.f;
#pragma unroll
          for (int q = 0; q < 4; q++) {
            const float4 p4 = *(const float4*)&prow[q * 4];  // broadcast LDS read
            s += p4.x * c[q * 4] + p4.y * c[q * 4 + 1] +
                 p4.z * c[q * 4 + 2] + p4.w * c[q * 4 + 3];
          }
          part += aa[u] * s;
        }
      }
      out_h += part;
    }
    __syncthreads();
  }

  outPN[(size_t)idx * HH + tid] = out_h * inv_l;
}

// ---------------------------------------------------------------------------
// loss: score[which,b] = b_fc + sum_{k,h} out[which,b,k,h]*W_fc[k*H+h]
//       loss = mean_b relu(score_n - score_p + margin)
// ---------------------------------------------------------------------------
__global__ __launch_bounds__(256) void loss_kernel(
    const float* __restrict__ outPN, const float* __restrict__ Wfc,
    const float* __restrict__ bfc, float* __restrict__ out)
{
  const int tid = threadIdx.x;
  const int lane = tid & 63;
  const int wave = tid >> 6;
  __shared__ float sc[64];                      // [which*32 + b]

  for (int pair = wave; pair < 64; pair += 4) {
    const float* o = outPN + (size_t)pair * (KK * HH);
    float s = 0.f;
    for (int i = lane; i < KK * HH; i += 64) s += o[i] * Wfc[i];
#pragma unroll
    for (int off = 32; off > 0; off >>= 1) s += __shfl_down(s, off);
    if (lane == 0) sc[pair] = s + bfc[0];
  }
  __syncthreads();
  if (tid == 0) {
    float acc = 0.f;
    for (int b2 = 0; b2 < 32; b2++) {
      const float d = sc[32 + b2] - sc[b2] + MARGINF;
      acc += fmaxf(d, 0.f);
    }
    out[0] = acc * (1.0f / 32.0f);
  }
}

// ---------------------------------------------------------------------------
extern "C" void kernel_launch(void* const* d_in, const int* in_sizes, int n_in,
                              void* d_out, int out_size, void* d_ws, size_t ws_size,
                              hipStream_t stream) {
  const float* he_a  = (const float*)d_in[0];
  const float* he_p  = (const float*)d_in[1];
  const float* he_n  = (const float*)d_in[2];
  const float* W_a2h = (const float*)d_in[3];
  const float* b_a2h = (const float*)d_in[4];
  const float* W_c2h = (const float*)d_in[5];
  const float* b_c2h = (const float*)d_in[6];
  const float* W_att = (const float*)d_in[7];
  // d_in[8] = b_att: constant shift per (b,k) -> cancels in global softmax
  const float* W_fc  = (const float*)d_in[9];
  const float* b_fc  = (const float*)d_in[10];

  float* ws    = (float*)d_ws;
  float* Aa    = ws;                                 // [B,H,N]  8 MB
  float* Ap    = Aa + (size_t)BB * HH * NN;          // [B,H,N]  8 MB
  float* An    = Ap + (size_t)BB * HH * NN;          // [B,H,N]  8 MB
  float* outPN = An + (size_t)BB * HH * NN;          // [2,B,K,H] 512 KB
  float* stats = outPN + (size_t)2 * BB * KK * HH;   // [2,B,K,2] 4 KB
  (void)ws_size; (void)in_sizes; (void)n_in; (void)out_size;

  dim3 pg(4, 4, BB);
  proj_kernel<<<pg, 256, 0, stream>>>(he_a, W_a2h, b_a2h, Aa);
  proj_kernel<<<pg, 256, 0, stream>>>(he_p, W_c2h, b_c2h, Ap);
  proj_kernel<<<pg, 256, 0, stream>>>(he_n, W_c2h, b_c2h, An);
  stats_kernel  <<<512, 256, 0, stream>>>(Aa, Ap, An, W_att, stats);
  attnout_kernel<<<512, 256, 0, stream>>>(Aa, Ap, An, W_att, stats, outPN);
  loss_kernel   <<<1,   256, 0, stream>>>(outPN, W_fc, b_fc, (float*)d_out);
}

// Round 3
// 582.819 us; speedup vs baseline: 2.7030x; 2.7030x over previous
//
#include <hip/hip_runtime.h>

#define BB 32
#define NN 256
#define EE 300
#define HH 256
#define KK 8
#define MARGINF 0.2f

typedef __attribute__((ext_vector_type(8))) short bf16x8;
typedef __attribute__((ext_vector_type(4))) float f32x4;

__device__ inline ushort f2bf(float f) {
  unsigned u = __float_as_uint(f);
  u += 0x7fffu + ((u >> 16) & 1u);          // RNE
  return (ushort)(u >> 16);
}
__device__ inline float bf2f(ushort s) { return __uint_as_float(((unsigned)s) << 16); }

// ---------------------------------------------------------------------------
// proj (fused 3 projections): A[b,h,n] = bias[h] + sum_e X[b,n,e]*W[h,e]
// fp32 compute, epilogue emits bf16 in TWO layouts:
//   AT[which][b][n][h]  (h-contiguous)  -- S-GEMM operands
//   AH[which-1][b][h][n] (n-contiguous) -- U-GEMM A-operand (pos/neg only)
// ---------------------------------------------------------------------------
__global__ __launch_bounds__(256) void proj_kernel(
    const float* __restrict__ he_a, const float* __restrict__ he_p,
    const float* __restrict__ he_n,
    const float* __restrict__ W_a2h, const float* __restrict__ b_a2h,
    const float* __restrict__ W_c2h, const float* __restrict__ b_c2h,
    ushort* __restrict__ AT, ushort* __restrict__ AH)
{
  const int z = blockIdx.z;
  const int which = z >> 5;            // 0=anchor,1=pos,2=neg (BB=32)
  const int b = z & 31;
  const int h0 = blockIdx.y * 64;
  const int n0 = blockIdx.x * 64;
  const int tid = threadIdx.x;

  const float* X = (which == 0 ? he_a : which == 1 ? he_p : he_n) + (size_t)b * NN * EE;
  const float* W = (which == 0 ? W_a2h : W_c2h);
  const float* bias = (which == 0 ? b_a2h : b_c2h);

  __shared__ __align__(16) float Ws[32][68];
  __shared__ __align__(16) float Xs[32][68];
  __shared__ __align__(16) ushort tr[64][72];   // [n_local][h_local] bf16

  const int th = tid & 15;
  const int tn = tid >> 4;
  const int le = tid & 31;
  const int lr = tid >> 5;

  float acc[4][4];
#pragma unroll
  for (int i = 0; i < 4; i++)
#pragma unroll
    for (int j = 0; j < 4; j++) acc[i][j] = 0.f;

  for (int e0 = 0; e0 < EE; e0 += 32) {
    const int e = e0 + le;
    const bool ok = (e < EE);
#pragma unroll
    for (int r = 0; r < 8; r++) {
      const int row = lr + 8 * r;
      Ws[le][row] = ok ? W[(size_t)(h0 + row) * EE + e] : 0.f;
      Xs[le][row] = ok ? X[(size_t)(n0 + row) * EE + e] : 0.f;
    }
    __syncthreads();
#pragma unroll
    for (int ee = 0; ee < 32; ee++) {
      float wv[4];
#pragma unroll
      for (int i = 0; i < 4; i++) wv[i] = Ws[ee][th + 16 * i];
      const float4 xv = *(const float4*)&Xs[ee][tn * 4];
      const float xa[4] = {xv.x, xv.y, xv.z, xv.w};
#pragma unroll
      for (int i = 0; i < 4; i++)
#pragma unroll
        for (int j = 0; j < 4; j++) acc[i][j] += wv[i] * xa[j];
    }
    __syncthreads();
  }

  // epilogue: bias + bf16, both layouts
#pragma unroll
  for (int i = 0; i < 4; i++) {
    const int h = h0 + th + 16 * i;
    const float bi = bias[h];
    ushort bf[4];
#pragma unroll
    for (int j = 0; j < 4; j++) {
      bf[j] = f2bf(acc[i][j] + bi);
      tr[tn * 4 + j][th + 16 * i] = bf[j];
    }
    if (which > 0) {
      ushort4 v4; v4.x = bf[0]; v4.y = bf[1]; v4.z = bf[2]; v4.w = bf[3];
      *(ushort4*)&AH[((size_t)(which - 1) * BB + b) * HH * NN + (size_t)h * NN + n0 + tn * 4] = v4;
    }
  }
  __syncthreads();
  // AT rows: thread t -> row t>>2, 16 ushorts (32B) at segment t&3
  {
    const int row = tid >> 2, seg = tid & 3;
    const uint4* src = (const uint4*)&tr[row][seg * 16];
    uint4* dst = (uint4*)&AT[((size_t)which * BB + b) * NN * HH + (size_t)(n0 + row) * HH + h0 + seg * 16];
    dst[0] = src[0];
    dst[1] = src[1];
  }
}

// ---------------------------------------------------------------------------
// fused flash attention per (which,b,k): 512 WGs, 256 threads (4 waves).
// Per 64x64 tile: S = (wk*Aa)^T Ac via MFMA (K=256), online global softmax
// (block max each tile), P->bf16->LDS ([n][m]), U = Ac * P^T via MFMA (K=64),
// V[h] += sum_n Aa[h,n]*U[h,n] (VALU, Aa from LDS).
// ---------------------------------------------------------------------------
__global__ __launch_bounds__(256) void attn_kernel(
    const ushort* __restrict__ AT, const ushort* __restrict__ AH,
    const float* __restrict__ Watt, float* __restrict__ outPN)
{
  const int idx = blockIdx.x;
  const int k = idx & 7;
  const int b = (idx >> 3) & 31;
  const int which = idx >> 8;
  const int tid = threadIdx.x;
  const int wv = tid >> 6;
  const int lane = tid & 63;
  const int col = lane & 15;
  const int quad = lane >> 4;

  const ushort* At_a = AT + ((size_t)0 * BB + b) * NN * HH;            // anchor [n][h]
  const ushort* At_c = AT + ((size_t)(1 + which) * BB + b) * NN * HH;  // pos/neg [m][h]
  const ushort* Ah_c = AH + ((size_t)which * BB + b) * HH * NN;        // pos/neg [h][m]

  __shared__ __align__(16) ushort sAn[64][264];  // [n_local][h] bf16 (anchor strip)
  __shared__ __align__(16) ushort sPL[64][72];   // [n_local][m_local] bf16 P tile
  __shared__ __align__(16) ushort wkb[256];
  __shared__ float red[8];

  if (tid < 256) wkb[tid] = f2bf(Watt[(size_t)k * HH + tid]);

  float m_run = -1e30f, l_part = 0.f;
  float Vv[4][4];
#pragma unroll
  for (int i = 0; i < 4; i++)
#pragma unroll
    for (int j = 0; j < 4; j++) Vv[i][j] = 0.f;

  for (int n0 = 0; n0 < NN; n0 += 64) {
    __syncthreads();  // sAn reuse guard (also covers wkb on first iter)
    {   // stage anchor strip [n0..n0+64) x [0..256) bf16: 512B/row, 4 thr/row,
        // 128B (8 x uint4) per thread.  (Round-2 bug: only 4 copied.)
      const int row = tid >> 2, seg = tid & 3;
      const uint4* src = (const uint4*)&At_a[(size_t)(n0 + row) * HH + seg * 64];
      uint4* dst = (uint4*)&sAn[row][seg * 64];
#pragma unroll
      for (int q = 0; q < 8; q++) dst[q] = src[q];
    }
    __syncthreads();

    // S A-fragments for this n-strip: (wk .* Aa)[n][h], kept in regs over m0
    bf16x8 saf[8];
#pragma unroll
    for (int ks = 0; ks < 8; ks++) {
      const bf16x8 a = *(const bf16x8*)&sAn[16 * wv + col][32 * ks + quad * 8];
      const bf16x8 w = *(const bf16x8*)&wkb[32 * ks + quad * 8];
      bf16x8 r;
#pragma unroll
      for (int j = 0; j < 8; j++)
        r[j] = (short)f2bf(bf2f((ushort)a[j]) * bf2f((ushort)w[j]));
      saf[ks] = r;
    }

    for (int m0 = 0; m0 < NN; m0 += 64) {
      f32x4 Sacc[4];
#pragma unroll
      for (int mb = 0; mb < 4; mb++) Sacc[mb] = (f32x4){0.f, 0.f, 0.f, 0.f};

#pragma unroll
      for (int ks = 0; ks < 8; ks++) {
#pragma unroll
        for (int mb = 0; mb < 4; mb++) {
          const bf16x8 bfr = *(const bf16x8*)&At_c[(size_t)(m0 + 16 * mb + col) * HH + 32 * ks + quad * 8];
          Sacc[mb] = __builtin_amdgcn_mfma_f32_16x16x32_bf16(saf[ks], bfr, Sacc[mb], 0, 0, 0);
        }
      }

      // block max for this tile
      float tmax = -1e30f;
#pragma unroll
      for (int mb = 0; mb < 4; mb++)
#pragma unroll
        for (int r = 0; r < 4; r++) tmax = fmaxf(tmax, Sacc[mb][r]);
#pragma unroll
      for (int off = 32; off >= 1; off >>= 1) tmax = fmaxf(tmax, __shfl_xor(tmax, off));
      if (lane == 0) red[wv] = tmax;
      __syncthreads();  // also guards sPL reads of previous tile before rewrite
      const float mt = fmaxf(fmaxf(red[0], red[1]), fmaxf(red[2], red[3]));
      const float mnew = fmaxf(m_run, mt);
      const float alpha = __expf(m_run - mnew);
      m_run = mnew;
      l_part *= alpha;
#pragma unroll
      for (int i = 0; i < 4; i++)
#pragma unroll
        for (int j = 0; j < 4; j++) Vv[i][j] *= alpha;

      // P = exp(S - m), write as [n][m] bf16
#pragma unroll
      for (int mb = 0; mb < 4; mb++)
#pragma unroll
        for (int r = 0; r < 4; r++) {
          const float p = __expf(Sacc[mb][r] - mnew);
          l_part += p;
          sPL[16 * wv + quad * 4 + r][16 * mb + col] = f2bf(p);
        }
      __syncthreads();  // sPL ready

      // U = Ac * P^T (per-wave h-strip 64), then contract with Aa
#pragma unroll
      for (int hb = 0; hb < 4; hb++) {
        const ushort* arow = Ah_c + (size_t)(64 * wv + 16 * hb + col) * NN + m0;
        const bf16x8 au0 = *(const bf16x8*)&arow[quad * 8];
        const bf16x8 au1 = *(const bf16x8*)&arow[32 + quad * 8];
#pragma unroll
        for (int nb = 0; nb < 4; nb++) {
          const bf16x8 p0 = *(const bf16x8*)&sPL[16 * nb + col][quad * 8];
          const bf16x8 p1 = *(const bf16x8*)&sPL[16 * nb + col][32 + quad * 8];
          f32x4 U = (f32x4){0.f, 0.f, 0.f, 0.f};
          U = __builtin_amdgcn_mfma_f32_16x16x32_bf16(au0, p0, U, 0, 0, 0);
          U = __builtin_amdgcn_mfma_f32_16x16x32_bf16(au1, p1, U, 0, 0, 0);
          const ushort* ap = &sAn[16 * nb + col][64 * wv + 16 * hb + 4 * quad];
#pragma unroll
          for (int r = 0; r < 4; r++) Vv[hb][r] += U[r] * bf2f(ap[r]);
        }
      }
    }
  }

  // reduce V over the 16 cols sharing each h
#pragma unroll
  for (int hb = 0; hb < 4; hb++)
#pragma unroll
    for (int r = 0; r < 4; r++) {
#pragma unroll
      for (int off = 1; off < 16; off <<= 1)
        Vv[hb][r] += __shfl_xor(Vv[hb][r], off);
    }

  // total l
  float lw = l_part;
#pragma unroll
  for (int off = 32; off >= 1; off >>= 1) lw += __shfl_xor(lw, off);
  if (lane == 0) red[4 + wv] = lw;
  __syncthreads();
  const float inv_l = 1.f / (red[4] + red[5] + red[6] + red[7]);

  // lane col c writes pair (hb=c>>2, r=c&3) for its quad
  const int hb = col >> 2, r = col & 3;
  outPN[(size_t)idx * HH + 64 * wv + 16 * hb + 4 * quad + r] = Vv[hb][r] * inv_l;
}

// ---------------------------------------------------------------------------
__global__ __launch_bounds__(256) void loss_kernel(
    const float* __restrict__ outPN, const float* __restrict__ Wfc,
    const float* __restrict__ bfc, float* __restrict__ out)
{
  const int tid = threadIdx.x;
  const int lane = tid & 63;
  const int wave = tid >> 6;
  __shared__ float sc[64];

  for (int pair = wave; pair < 64; pair += 4) {
    const float* o = outPN + (size_t)pair * (KK * HH);
    float s = 0.f;
    for (int i = lane; i < KK * HH; i += 64) s += o[i] * Wfc[i];
#pragma unroll
    for (int off = 32; off > 0; off >>= 1) s += __shfl_down(s, off);
    if (lane == 0) sc[pair] = s + bfc[0];
  }
  __syncthreads();
  if (tid == 0) {
    float acc = 0.f;
    for (int b2 = 0; b2 < 32; b2++) {
      const float d = sc[32 + b2] - sc[b2] + MARGINF;
      acc += fmaxf(d, 0.f);
    }
    out[0] = acc * (1.0f / 32.0f);
  }
}

// ---------------------------------------------------------------------------
extern "C" void kernel_launch(void* const* d_in, const int* in_sizes, int n_in,
                              void* d_out, int out_size, void* d_ws, size_t ws_size,
                              hipStream_t stream) {
  const float* he_a  = (const float*)d_in[0];
  const float* he_p  = (const float*)d_in[1];
  const float* he_n  = (const float*)d_in[2];
  const float* W_a2h = (const float*)d_in[3];
  const float* b_a2h = (const float*)d_in[4];
  const float* W_c2h = (const float*)d_in[5];
  const float* b_c2h = (const float*)d_in[6];
  const float* W_att = (const float*)d_in[7];
  // d_in[8] = b_att: cancels in global softmax
  const float* W_fc  = (const float*)d_in[9];
  const float* b_fc  = (const float*)d_in[10];

  ushort* AT = (ushort*)d_ws;                              // [3][B][N][H] bf16, 12.6 MB
  ushort* AH = AT + (size_t)3 * BB * NN * HH;              // [2][B][H][N] bf16,  8.4 MB
  float* outPN = (float*)(AH + (size_t)2 * BB * HH * NN);  // [2,B,K,H] fp32, 512 KB
  (void)ws_size; (void)in_sizes; (void)n_in; (void)out_size;

  dim3 pg(4, 4, 3 * BB);
  proj_kernel<<<pg, 256, 0, stream>>>(he_a, he_p, he_n, W_a2h, b_a2h, W_c2h, b_c2h, AT, AH);
  attn_kernel<<<512, 256, 0, stream>>>(AT, AH, W_att, outPN);
  loss_kernel<<<1, 256, 0, stream>>>(outPN, W_fc, b_fc, (float*)d_out);
}

// Round 4
// 284.464 us; speedup vs baseline: 5.5380x; 2.0488x over previous
//
#include <hip/hip_runtime.h>

#define BB 32
#define NN 256
#define EE 300
#define HH 256
#define KK 8
#define MARGINF 0.2f

typedef __attribute__((ext_vector_type(8))) short bf16x8;
typedef __attribute__((ext_vector_type(4))) float f32x4;

__device__ inline ushort f2bf(float f) {
  unsigned u = __float_as_uint(f);
  u += 0x7fffu + ((u >> 16) & 1u);          // RNE
  return (ushort)(u >> 16);
}
__device__ inline float bf2f(ushort s) { return __uint_as_float(((unsigned)s) << 16); }

// ---------------------------------------------------------------------------
// proj (fused 3 projections): A[b,h,n] = bias[h] + sum_e X[b,n,e]*W[h,e]
// fp32 compute, emits bf16 AT[which][b][n][h] (h-contiguous) only.
// ---------------------------------------------------------------------------
__global__ __launch_bounds__(256) void proj_kernel(
    const float* __restrict__ he_a, const float* __restrict__ he_p,
    const float* __restrict__ he_n,
    const float* __restrict__ W_a2h, const float* __restrict__ b_a2h,
    const float* __restrict__ W_c2h, const float* __restrict__ b_c2h,
    ushort* __restrict__ AT)
{
  const int z = blockIdx.z;
  const int which = z >> 5;            // 0=anchor,1=pos,2=neg
  const int b = z & 31;
  const int h0 = blockIdx.y * 64;
  const int n0 = blockIdx.x * 64;
  const int tid = threadIdx.x;

  const float* X = (which == 0 ? he_a : which == 1 ? he_p : he_n) + (size_t)b * NN * EE;
  const float* W = (which == 0 ? W_a2h : W_c2h);
  const float* bias = (which == 0 ? b_a2h : b_c2h);

  __shared__ __align__(16) float Ws[32][68];    // [e][h]
  __shared__ __align__(16) float Xs[32][68];    // [e][n]
  __shared__ __align__(16) ushort tr[64][72];   // [n_local][h_local] bf16

  const int th = tid & 15;   // h = h0 + th*4 + i  (float4 W reads)
  const int tn = tid >> 4;   // n = n0 + tn*4 + j
  const int le = tid & 31;
  const int lr = tid >> 5;

  float acc[4][4];
#pragma unroll
  for (int i = 0; i < 4; i++)
#pragma unroll
    for (int j = 0; j < 4; j++) acc[i][j] = 0.f;

  for (int e0 = 0; e0 < EE; e0 += 32) {
    const int e = e0 + le;
    const bool ok = (e < EE);
#pragma unroll
    for (int r = 0; r < 8; r++) {
      const int row = lr + 8 * r;
      Ws[le][row] = ok ? W[(size_t)(h0 + row) * EE + e] : 0.f;
      Xs[le][row] = ok ? X[(size_t)(n0 + row) * EE + e] : 0.f;
    }
    __syncthreads();
#pragma unroll
    for (int ee = 0; ee < 32; ee++) {
      const float4 wf = *(const float4*)&Ws[ee][th * 4];
      const float4 xv = *(const float4*)&Xs[ee][tn * 4];
      const float wa[4] = {wf.x, wf.y, wf.z, wf.w};
      const float xa[4] = {xv.x, xv.y, xv.z, xv.w};
#pragma unroll
      for (int i = 0; i < 4; i++)
#pragma unroll
        for (int j = 0; j < 4; j++) acc[i][j] += wa[i] * xa[j];
    }
    __syncthreads();
  }

#pragma unroll
  for (int i = 0; i < 4; i++) {
    const int hl = th * 4 + i;
    const float bi = bias[h0 + hl];
#pragma unroll
    for (int j = 0; j < 4; j++) tr[tn * 4 + j][hl] = f2bf(acc[i][j] + bi);
  }
  __syncthreads();
  {
    const int row = tid >> 2, seg = tid & 3;
    const uint4* src = (const uint4*)&tr[row][seg * 16];
    uint4* dst = (uint4*)&AT[((size_t)which * BB + b) * NN * HH + (size_t)(n0 + row) * HH + h0 + seg * 16];
    dst[0] = src[0];
    dst[1] = src[1];
  }
}

// ---------------------------------------------------------------------------
// fused flash attention per (which,b,k).  blockIdx = k*64 + g, g = which*32+b
// -> blockIdx%8 = g%8: all 8 k-replicas of a (which,b) group on ONE XCD ->
// At strips stay L2-resident (per-XCD set ~2 MB < 4 MB L2).
// m0 outer: stage sAc (coalesced), extract U A-frags (au) from sAc via
// transposed LDS reads; n0 inner: stage sAn (reg-prefetched), S-MFMA from
// LDS, exp WITHOUT max subtraction (|S|<~1.2 by construction), U-MFMA,
// V contraction. No online-softmax rescaling at all.
// ---------------------------------------------------------------------------
__global__ __launch_bounds__(256, 2) void attn_kernel(
    const ushort* __restrict__ AT, const float* __restrict__ Watt,
    float* __restrict__ outPN)
{
  const int idx = blockIdx.x;
  const int k = idx >> 6;
  const int g = idx & 63;
  const int which = g >> 5;
  const int b = g & 31;
  const int tid = threadIdx.x;
  const int wv = tid >> 6;
  const int lane = tid & 63;
  const int col = lane & 15;
  const int quad = lane >> 4;

  const ushort* At_a = AT + ((size_t)0 * BB + b) * NN * HH;            // anchor [n][h]
  const ushort* At_c = AT + ((size_t)(1 + which) * BB + b) * NN * HH;  // pos/neg [m][h]
  const uint4* Aa_u4 = (const uint4*)At_a;
  const uint4* Ac_u4 = (const uint4*)At_c;

  __shared__ __align__(16) ushort sAc[64][260];  // [m_local][h]
  __shared__ __align__(16) ushort sAn[64][260];  // [n_local][h]
  __shared__ __align__(16) ushort sPL[64][68];   // [n_local][m_local]
  __shared__ ushort wkb[256];
  __shared__ float red[4];

  wkb[tid] = f2bf(Watt[(size_t)k * HH + tid]);

  float l_part = 0.f;
  float Vv[4][4];
#pragma unroll
  for (int i = 0; i < 4; i++)
#pragma unroll
    for (int j = 0; j < 4; j++) Vv[i][j] = 0.f;

  const int srow = tid >> 5, scol = (tid & 31) * 8;   // staging dst mapping

  for (int m0i = 0; m0i < 4; m0i++) {
    __syncthreads();  // sAc reuse guard
    {
      const uint4* src = Ac_u4 + m0i * 2048 + tid;
#pragma unroll
      for (int q = 0; q < 8; q++)
        *(uint4*)&sAc[q * 8 + srow][scol] = src[q * 256];
    }
    __syncthreads();

    // U A-fragments: au[hb][half][j] = Ac[h=64wv+16hb+col][m0 + half*32 + quad*8 + j]
    bf16x8 au[4][2];
#pragma unroll
    for (int hb = 0; hb < 4; hb++)
#pragma unroll
      for (int half = 0; half < 2; half++) {
        bf16x8 r;
#pragma unroll
        for (int j = 0; j < 8; j++)
          r[j] = (short)sAc[half * 32 + quad * 8 + j][64 * wv + 16 * hb + col];
        au[hb][half] = r;
      }

    // prefetch sAn strip for n0=0
    uint4 pf[8];
#pragma unroll
    for (int q = 0; q < 8; q++) pf[q] = Aa_u4[q * 256 + tid];

    for (int n0i = 0; n0i < 4; n0i++) {
      __syncthreads();  // sAn + sPL reuse guard (prev U-phase done)
#pragma unroll
      for (int q = 0; q < 8; q++)
        *(uint4*)&sAn[q * 8 + srow][scol] = pf[q];
      __syncthreads();
      if (n0i < 3) {
        const uint4* src = Aa_u4 + (n0i + 1) * 2048 + tid;
#pragma unroll
        for (int q = 0; q < 8; q++) pf[q] = src[q * 256];
      }

      // S A-fragments: (wk .* Aa)[n=16wv+col][k-chunk]
      bf16x8 saf[8];
#pragma unroll
      for (int ks = 0; ks < 8; ks++) {
        const bf16x8 a = *(const bf16x8*)&sAn[16 * wv + col][32 * ks + quad * 8];
        const bf16x8 w = *(const bf16x8*)&wkb[32 * ks + quad * 8];
        bf16x8 r;
#pragma unroll
        for (int j = 0; j < 8; j++)
          r[j] = (short)f2bf(bf2f((ushort)a[j]) * bf2f((ushort)w[j]));
        saf[ks] = r;
      }

      // S = (wk*Aa)^T Ac
      f32x4 Sacc[4];
#pragma unroll
      for (int mb = 0; mb < 4; mb++) Sacc[mb] = (f32x4){0.f, 0.f, 0.f, 0.f};
#pragma unroll
      for (int ks = 0; ks < 8; ks++)
#pragma unroll
        for (int mb = 0; mb < 4; mb++) {
          const bf16x8 bfr = *(const bf16x8*)&sAc[16 * mb + col][32 * ks + quad * 8];
          Sacc[mb] = __builtin_amdgcn_mfma_f32_16x16x32_bf16(saf[ks], bfr, Sacc[mb], 0, 0, 0);
        }

      // P = exp(S) (no max; |S| small), stash bf16 [n][m]
#pragma unroll
      for (int mb = 0; mb < 4; mb++)
#pragma unroll
        for (int r = 0; r < 4; r++) {
          const float p = __expf(Sacc[mb][r]);
          l_part += p;
          sPL[16 * wv + quad * 4 + r][16 * mb + col] = f2bf(p);
        }
      __syncthreads();  // sPL ready

      // U = Ac * P^T, contract with Aa
#pragma unroll
      for (int hb = 0; hb < 4; hb++)
#pragma unroll
        for (int nb = 0; nb < 4; nb++) {
          const bf16x8 p0 = *(const bf16x8*)&sPL[16 * nb + col][quad * 8];
          const bf16x8 p1 = *(const bf16x8*)&sPL[16 * nb + col][32 + quad * 8];
          f32x4 U = (f32x4){0.f, 0.f, 0.f, 0.f};
          U = __builtin_amdgcn_mfma_f32_16x16x32_bf16(au[hb][0], p0, U, 0, 0, 0);
          U = __builtin_amdgcn_mfma_f32_16x16x32_bf16(au[hb][1], p1, U, 0, 0, 0);
          const ushort4 ap = *(const ushort4*)&sAn[16 * nb + col][64 * wv + 16 * hb + 4 * quad];
          Vv[hb][0] += U[0] * bf2f(ap.x);
          Vv[hb][1] += U[1] * bf2f(ap.y);
          Vv[hb][2] += U[2] * bf2f(ap.z);
          Vv[hb][3] += U[3] * bf2f(ap.w);
        }
    }
  }

  // reduce V over the 16 cols sharing each h
#pragma unroll
  for (int hb = 0; hb < 4; hb++)
#pragma unroll
    for (int r = 0; r < 4; r++) {
#pragma unroll
      for (int off = 1; off < 16; off <<= 1)
        Vv[hb][r] += __shfl_xor(Vv[hb][r], off);
    }

  // total l
  float lw = l_part;
#pragma unroll
  for (int off = 32; off >= 1; off >>= 1) lw += __shfl_xor(lw, off);
  if (lane == 0) red[wv] = lw;
  __syncthreads();
  const float inv_l = 1.f / (red[0] + red[1] + red[2] + red[3]);

  const int hb = col >> 2, r = col & 3;
  outPN[(size_t)idx * HH + 64 * wv + 16 * hb + 4 * quad + r] = Vv[hb][r] * inv_l;
}

// ---------------------------------------------------------------------------
// fc: scores[g] = b_fc + sum_{k,h} outPN[(k*64+g)][h] * Wfc[k*H+h]
// ---------------------------------------------------------------------------
__global__ __launch_bounds__(256) void fc_kernel(
    const float* __restrict__ outPN, const float* __restrict__ Wfc,
    const float* __restrict__ bfc, float* __restrict__ scores)
{
  const int gidx = blockIdx.x;
  const int tid = threadIdx.x;
  const int lane = tid & 63;
  const int wvv = tid >> 6;
  __shared__ float rp[4];

  float s = 0.f;
#pragma unroll
  for (int k = 0; k < KK; k++)
    s += outPN[(size_t)(k * 64 + gidx) * HH + tid] * Wfc[k * HH + tid];
#pragma unroll
  for (int off = 32; off >= 1; off >>= 1) s += __shfl_xor(s, off);
  if (lane == 0) rp[wvv] = s;
  __syncthreads();
  if (tid == 0) scores[gidx] = rp[0] + rp[1] + rp[2] + rp[3] + bfc[0];
}

__global__ __launch_bounds__(64) void loss_kernel(
    const float* __restrict__ scores, float* __restrict__ out)
{
  const int tid = threadIdx.x;
  float v = 0.f;
  if (tid < 32) v = fmaxf(scores[32 + tid] - scores[tid] + MARGINF, 0.f);
#pragma unroll
  for (int off = 32; off >= 1; off >>= 1) v += __shfl_xor(v, off);
  if (tid == 0) out[0] = v * (1.0f / 32.0f);
}

// ---------------------------------------------------------------------------
extern "C" void kernel_launch(void* const* d_in, const int* in_sizes, int n_in,
                              void* d_out, int out_size, void* d_ws, size_t ws_size,
                              hipStream_t stream) {
  const float* he_a  = (const float*)d_in[0];
  const float* he_p  = (const float*)d_in[1];
  const float* he_n  = (const float*)d_in[2];
  const float* W_a2h = (const float*)d_in[3];
  const float* b_a2h = (const float*)d_in[4];
  const float* W_c2h = (const float*)d_in[5];
  const float* b_c2h = (const float*)d_in[6];
  const float* W_att = (const float*)d_in[7];
  // d_in[8] = b_att: cancels in global softmax
  const float* W_fc  = (const float*)d_in[9];
  const float* b_fc  = (const float*)d_in[10];

  ushort* AT = (ushort*)d_ws;                               // [3][B][N][H] bf16, 12.6 MB
  float* outPN  = (float*)(AT + (size_t)3 * BB * NN * HH);  // [512][H] fp32, 512 KB
  float* scores = outPN + (size_t)2 * BB * KK * HH;         // [64]
  (void)ws_size; (void)in_sizes; (void)n_in; (void)out_size;

  dim3 pg(4, 4, 3 * BB);
  proj_kernel<<<pg, 256, 0, stream>>>(he_a, he_p, he_n, W_a2h, b_a2h, W_c2h, b_c2h, AT);
  attn_kernel<<<512, 256, 0, stream>>>(AT, W_att, outPN);
  fc_kernel<<<64, 256, 0, stream>>>(outPN, W_fc, b_fc, scores);
  loss_kernel<<<1, 64, 0, stream>>>(scores, (float*)d_out);
}

// Round 5
// 167.924 us; speedup vs baseline: 9.3814x; 1.6940x over previous
//
#include <hip/hip_runtime.h>

#define BB 32
#define NN 256
#define EE 300
#define HH 256
#define KK 8
#define MARGINF 0.2f

typedef __attribute__((ext_vector_type(8))) short bf16x8;
typedef __attribute__((ext_vector_type(4))) float f32x4;

__device__ inline ushort f2bf(float f) {
  unsigned u = __float_as_uint(f);
  u += 0x7fffu + ((u >> 16) & 1u);          // RNE
  return (ushort)(u >> 16);
}
__device__ inline float bf2f(ushort s) { return __uint_as_float(((unsigned)s) << 16); }
__device__ inline unsigned pack2bf(float f0, float f1) {   // [f0 lo | f1 hi], RNE
  unsigned u0 = __float_as_uint(f0); u0 += 0x7fffu + ((u0 >> 16) & 1u);
  unsigned u1 = __float_as_uint(f1); u1 += 0x7fffu + ((u1 >> 16) & 1u);
  return (u0 >> 16) | (u1 & 0xffff0000u);
}

// ---------------------------------------------------------------------------
// proj via bf16 MFMA: AT[which][b][n][h] = bf16(bias[h] + sum_e X[b,n,e]W[h,e])
// grid (4 n-tiles, 4 h-tiles, 3*B), 256 thr. K=300 staged in 2 chunks of 160
// (5 MFMA k-steps each, zero-padded past 300). fp32 accumulate in AGPRs.
// D mapping (verified by rounds 3/4 passing): D[row=16wv+4q+r (A idx)][col (B idx)]
// ---------------------------------------------------------------------------
__global__ __launch_bounds__(256) void proj_kernel(
    const float* __restrict__ he_a, const float* __restrict__ he_p,
    const float* __restrict__ he_n,
    const float* __restrict__ W_a2h, const float* __restrict__ b_a2h,
    const float* __restrict__ W_c2h, const float* __restrict__ b_c2h,
    ushort* __restrict__ AT)
{
  const int z = blockIdx.z;
  const int which = z >> 5;
  const int b = z & 31;
  const int h0 = blockIdx.y * 64;
  const int n0 = blockIdx.x * 64;
  const int tid = threadIdx.x;
  const int wv = tid >> 6;
  const int lane = tid & 63;
  const int col = lane & 15;
  const int quad = lane >> 4;

  const float* X = (which == 0 ? he_a : which == 1 ? he_p : he_n) + (size_t)b * NN * EE;
  const float* W = (which == 0 ? W_a2h : W_c2h);
  const float* bias = (which == 0 ? b_a2h : b_c2h);

  __shared__ __align__(16) ushort sX[64][184];  // [n_local][e_chunk] bf16 (stride 92 dw, %32=28 -> 2-way)
  __shared__ __align__(16) ushort sW[64][184];  // [h_local][e_chunk]
  __shared__ __align__(16) ushort tr[64][72];   // [n_local][h_local] epilogue transpose

  f32x4 acc[4];
#pragma unroll
  for (int mb = 0; mb < 4; mb++) acc[mb] = (f32x4){0.f, 0.f, 0.f, 0.f};

  const int row_s = tid >> 2, c4 = tid & 3;

  for (int kb = 0; kb < 2; kb++) {
    __syncthreads();   // previous chunk's MFMA reads done
#pragma unroll
    for (int q = 0; q < 10; q++) {
      const int j = c4 + 4 * q;           // float4 slot within chunk, 0..39
      const int e = 160 * kb + 4 * j;
      float4 xv = {0.f, 0.f, 0.f, 0.f}, wf = {0.f, 0.f, 0.f, 0.f};
      if (e < 300) {                      // 300 % 4 == 0: no partial vector
        xv = *(const float4*)&X[(size_t)(n0 + row_s) * EE + e];
        wf = *(const float4*)&W[(size_t)(h0 + row_s) * EE + e];
      }
      uint2 px, pw;
      px.x = pack2bf(xv.x, xv.y); px.y = pack2bf(xv.z, xv.w);
      pw.x = pack2bf(wf.x, wf.y); pw.y = pack2bf(wf.z, wf.w);
      *(uint2*)&sX[row_s][4 * j] = px;
      *(uint2*)&sW[row_s][4 * j] = pw;
    }
    __syncthreads();
#pragma unroll
    for (int ksl = 0; ksl < 5; ksl++) {
      const bf16x8 xa = *(const bf16x8*)&sX[16 * wv + col][32 * ksl + 8 * quad];
#pragma unroll
      for (int mb = 0; mb < 4; mb++) {
        const bf16x8 wb = *(const bf16x8*)&sW[16 * mb + col][32 * ksl + 8 * quad];
        acc[mb] = __builtin_amdgcn_mfma_f32_16x16x32_bf16(xa, wb, acc[mb], 0, 0, 0);
      }
    }
  }

  // epilogue: + bias, bf16, transpose through LDS, coalesced store
#pragma unroll
  for (int mb = 0; mb < 4; mb++) {
    const float bi = bias[h0 + 16 * mb + col];
#pragma unroll
    for (int r = 0; r < 4; r++)
      tr[16 * wv + 4 * quad + r][16 * mb + col] = f2bf(acc[mb][r] + bi);
  }
  __syncthreads();
  {
    const int row = tid >> 2, seg = tid & 3;
    const uint4* src = (const uint4*)&tr[row][seg * 16];
    uint4* dst = (uint4*)&AT[((size_t)(which * BB + b) * NN + n0 + row) * HH + h0 + seg * 16];
    dst[0] = src[0];
    dst[1] = src[1];
  }
}

// ---------------------------------------------------------------------------
// attn+score per (which,b,k): score_k = num/den with
//   num = sum_{n,m} exp(S[n,m]) * G[n,m],  den = sum exp(S)
//   S = (wk.*Aa)^T Ac (Watt row k),  G = (wfc_k.*Aa)^T Ac (Wfc slice k)
// (b_att cancels in softmax; exp without max: |S| <~ 1.2 by construction,
//  validated in round 4.)  B-fragments (Ac) shared by S- and G-MFMA.
// blockIdx = k*64 + g -> idx%8 = g%8: 8 k-replicas of (which,b) on one XCD.
// LDS: half of Ac (128 rows) resident -> 4 barriers total per WG.
// A-fragments gathered from global (L2-hot strips).
// ---------------------------------------------------------------------------
__global__ __launch_bounds__(256, 2) void attn_kernel(
    const ushort* __restrict__ AT, const float* __restrict__ Watt,
    const float* __restrict__ Wfc, float* __restrict__ scoresK)
{
  const int idx = blockIdx.x;
  const int k = idx >> 6;
  const int g = idx & 63;
  const int which = g >> 5;
  const int b = g & 31;
  const int tid = threadIdx.x;
  const int wv = tid >> 6;
  const int lane = tid & 63;
  const int col = lane & 15;
  const int quad = lane >> 4;

  const ushort* At_a = AT + (size_t)b * NN * HH;                       // anchor [n][h]
  const ushort* At_c = AT + ((size_t)(1 + which) * BB + b) * NN * HH;  // pos/neg [m][h]
  const uint4* Ac_u4 = (const uint4*)At_c;

  __shared__ __align__(16) ushort sAc[128][264];  // [m_local][h], stride 132 dw (%32=4 -> 2-way free)
  __shared__ ushort wkb[256];
  __shared__ ushort wfb[256];
  __shared__ float red[8];

  wkb[tid] = f2bf(Watt[(size_t)k * HH + tid]);
  wfb[tid] = f2bf(Wfc[(size_t)k * HH + tid]);

  float num = 0.f, den = 0.f;
  const int srow = tid >> 5, scol = (tid & 31) * 8;

  for (int half = 0; half < 2; half++) {
    __syncthreads();   // prev half's B-frag reads done (covers wkb/wfb on first iter)
    {                  // stage m-rows [128*half, 128*half+128): 16 uint4 / thread
      const uint4* src = Ac_u4 + (size_t)half * 4096 + (tid & 31);
#pragma unroll
      for (int q = 0; q < 16; q++)
        *(uint4*)&sAc[q * 8 + srow][scol] = src[(q * 8 + srow) * 32];
    }
    __syncthreads();

    for (int j = 0; j < 4; j++) {       // n-group: rows 64j + 16wv + col
      const ushort* arow = At_a + (size_t)(64 * j + 16 * wv + col) * HH;
      bf16x8 saf[8], gaf[8];
#pragma unroll
      for (int ks = 0; ks < 8; ks++) {
        const bf16x8 a  = *(const bf16x8*)&arow[32 * ks + 8 * quad];   // global, L2-hot
        const bf16x8 w8 = *(const bf16x8*)&wkb[32 * ks + 8 * quad];
        const bf16x8 f8 = *(const bf16x8*)&wfb[32 * ks + 8 * quad];
        union { bf16x8 v; unsigned u[4]; } s, gq;
#pragma unroll
        for (int jj = 0; jj < 4; jj++) {
          const float a0 = bf2f((ushort)a[2 * jj]), a1 = bf2f((ushort)a[2 * jj + 1]);
          s.u[jj]  = pack2bf(a0 * bf2f((ushort)w8[2 * jj]), a1 * bf2f((ushort)w8[2 * jj + 1]));
          gq.u[jj] = pack2bf(a0 * bf2f((ushort)f8[2 * jj]), a1 * bf2f((ushort)f8[2 * jj + 1]));
        }
        saf[ks] = s.v; gaf[ks] = gq.v;
      }

#pragma unroll 1
      for (int ms = 0; ms < 2; ms++) {
        f32x4 S[4], G[4];
#pragma unroll
        for (int mb = 0; mb < 4; mb++) { S[mb] = (f32x4){0.f,0.f,0.f,0.f}; G[mb] = (f32x4){0.f,0.f,0.f,0.f}; }
#pragma unroll
        for (int ks = 0; ks < 8; ks++) {
#pragma unroll
          for (int mb = 0; mb < 4; mb++) {
            const bf16x8 bfr = *(const bf16x8*)&sAc[64 * ms + 16 * mb + col][32 * ks + 8 * quad];
            S[mb] = __builtin_amdgcn_mfma_f32_16x16x32_bf16(saf[ks], bfr, S[mb], 0, 0, 0);
            G[mb] = __builtin_amdgcn_mfma_f32_16x16x32_bf16(gaf[ks], bfr, G[mb], 0, 0, 0);
          }
        }
#pragma unroll
        for (int mb = 0; mb < 4; mb++)
#pragma unroll
          for (int r = 0; r < 4; r++) {
            const float p = __expf(S[mb][r]);
            den += p;
            num += p * G[mb][r];
          }
      }
    }
  }

  // reduce num/den across 64 lanes, then 4 waves
#pragma unroll
  for (int off = 32; off >= 1; off >>= 1) {
    num += __shfl_xor(num, off);
    den += __shfl_xor(den, off);
  }
  if (lane == 0) { red[wv] = num; red[4 + wv] = den; }
  __syncthreads();
  if (tid == 0) {
    const float nt = red[0] + red[1] + red[2] + red[3];
    const float dt = red[4] + red[5] + red[6] + red[7];
    scoresK[idx] = nt / dt;
  }
}

// ---------------------------------------------------------------------------
// loss: score(g) = b_fc + sum_k scoresK[k*64+g]; mean_b relu(sn - sp + margin)
// ---------------------------------------------------------------------------
__global__ __launch_bounds__(64) void loss_kernel(
    const float* __restrict__ scoresK, const float* __restrict__ bfc,
    float* __restrict__ out)
{
  const int tid = threadIdx.x;    // tid = which*32 + b
  float s = bfc[0];
#pragma unroll
  for (int k = 0; k < KK; k++) s += scoresK[k * 64 + tid];
  const float other = __shfl(s, tid + 32);   // wraps mod 64; valid for tid<32
  float v = 0.f;
  if (tid < 32) v = fmaxf(other - s + MARGINF, 0.f);
#pragma unroll
  for (int off = 32; off >= 1; off >>= 1) v += __shfl_xor(v, off);
  if (tid == 0) out[0] = v * (1.0f / 32.0f);
}

// ---------------------------------------------------------------------------
extern "C" void kernel_launch(void* const* d_in, const int* in_sizes, int n_in,
                              void* d_out, int out_size, void* d_ws, size_t ws_size,
                              hipStream_t stream) {
  const float* he_a  = (const float*)d_in[0];
  const float* he_p  = (const float*)d_in[1];
  const float* he_n  = (const float*)d_in[2];
  const float* W_a2h = (const float*)d_in[3];
  const float* b_a2h = (const float*)d_in[4];
  const float* W_c2h = (const float*)d_in[5];
  const float* b_c2h = (const float*)d_in[6];
  const float* W_att = (const float*)d_in[7];
  // d_in[8] = b_att: cancels in global softmax
  const float* W_fc  = (const float*)d_in[9];
  const float* b_fc  = (const float*)d_in[10];

  ushort* AT = (ushort*)d_ws;                               // [3][B][N][H] bf16, 12.6 MB
  float* scoresK = (float*)(AT + (size_t)3 * BB * NN * HH); // [512] fp32
  (void)ws_size; (void)in_sizes; (void)n_in; (void)out_size;

  dim3 pg(4, 4, 3 * BB);
  proj_kernel<<<pg, 256, 0, stream>>>(he_a, he_p, he_n, W_a2h, b_a2h, W_c2h, b_c2h, AT);
  attn_kernel<<<512, 256, 0, stream>>>(AT, W_att, W_fc, scoresK);
  loss_kernel<<<1, 64, 0, stream>>>(scoresK, b_fc, (float*)d_out);
}

// Round 6
// 162.786 us; speedup vs baseline: 9.6775x; 1.0316x over previous
//
#include <hip/hip_runtime.h>

#define BB 32
#define NN 256
#define EE 300
#define HH 256
#define KK 8
#define MARGINF 0.2f

typedef __attribute__((ext_vector_type(8))) short bf16x8;
typedef __attribute__((ext_vector_type(4))) float f32x4;
typedef __attribute__((ext_vector_type(16))) float f32x16;

__device__ inline ushort f2bf(float f) {
  unsigned u = __float_as_uint(f);
  u += 0x7fffu + ((u >> 16) & 1u);          // RNE
  return (ushort)(u >> 16);
}
__device__ inline float bf2f(ushort s) { return __uint_as_float(((unsigned)s) << 16); }
__device__ inline unsigned pack2bf(float f0, float f1) {   // [f0 lo | f1 hi], RNE
  unsigned u0 = __float_as_uint(f0); u0 += 0x7fffu + ((u0 >> 16) & 1u);
  unsigned u1 = __float_as_uint(f1); u1 += 0x7fffu + ((u1 >> 16) & 1u);
  return (u0 >> 16) | (u1 & 0xffff0000u);
}

// ---------------------------------------------------------------------------
// proj: one WG per (which,b,32-row n-tile) computing the FULL H=256 output.
// X tile read exactly once globally (29.5 MB total); W streamed from L2 in
// K-chunks of 64. 16x16x32 MFMA with the round-5-verified operand/C layouts.
// grid (8, 96), 256 thr. LDS: sX 32x72 + sW 256x72 bf16; tr aliases sW.
// ---------------------------------------------------------------------------
__global__ __launch_bounds__(256, 3) void proj_kernel(
    const float* __restrict__ he_a, const float* __restrict__ he_p,
    const float* __restrict__ he_n,
    const float* __restrict__ W_a2h, const float* __restrict__ b_a2h,
    const float* __restrict__ W_c2h, const float* __restrict__ b_c2h,
    ushort* __restrict__ AT)
{
  const int z = blockIdx.y;
  const int which = z >> 5;
  const int b = z & 31;
  const int n0 = blockIdx.x * 32;
  const int tid = threadIdx.x;
  const int wv = tid >> 6;
  const int lane = tid & 63;
  const int col = lane & 15;
  const int quad = lane >> 4;

  const float* X = (which == 0 ? he_a : which == 1 ? he_p : he_n) + (size_t)b * NN * EE;
  const float* W = (which == 0 ? W_a2h : W_c2h);
  const float* bias = (which == 0 ? b_a2h : b_c2h);

  __shared__ __align__(16) ushort sX[32][72];    // [n_local][e_chunk]
  __shared__ __align__(16) ushort sW[256][72];   // [h][e_chunk]
  ushort (*tr)[264] = (ushort (*)[264])&sW[0][0];  // 32x264 aliases sW post-MFMA

  f32x4 acc[2][4];
#pragma unroll
  for (int nf = 0; nf < 2; nf++)
#pragma unroll
    for (int mb = 0; mb < 4; mb++) acc[nf][mb] = (f32x4){0.f, 0.f, 0.f, 0.f};

  const int c4 = tid & 15;            // float4 slot in chunk (constant/thread)
  const int rbase = tid >> 4;

  for (int c = 0; c < 5; c++) {       // K chunks of 64 (K padded 300->320)
    __syncthreads();                  // prev chunk MFMA reads done
    const int e = 64 * c + 4 * c4;
    const bool ok = (e < 300);
    {  // X: 32 rows x 16 float4
#pragma unroll
      for (int q = 0; q < 2; q++) {
        const int row = rbase + 16 * q;
        float4 xv = {0.f, 0.f, 0.f, 0.f};
        if (ok) xv = *(const float4*)&X[(size_t)(n0 + row) * EE + e];
        uint2 p; p.x = pack2bf(xv.x, xv.y); p.y = pack2bf(xv.z, xv.w);
        *(uint2*)&sX[row][c4 * 4] = p;
      }
    }
    {  // W: 256 rows x 16 float4
#pragma unroll
      for (int q = 0; q < 16; q++) {
        const int row = rbase + 16 * q;
        float4 wf = {0.f, 0.f, 0.f, 0.f};
        if (ok) wf = *(const float4*)&W[(size_t)row * EE + e];
        uint2 p; p.x = pack2bf(wf.x, wf.y); p.y = pack2bf(wf.z, wf.w);
        *(uint2*)&sW[row][c4 * 4] = p;
      }
    }
    __syncthreads();
#pragma unroll
    for (int ks = 0; ks < 2; ks++) {
      const int off = 32 * ks + 8 * quad;
      const bf16x8 a0 = *(const bf16x8*)&sX[col][off];
      const bf16x8 a1 = *(const bf16x8*)&sX[16 + col][off];
#pragma unroll
      for (int mb = 0; mb < 4; mb++) {
        const bf16x8 wb = *(const bf16x8*)&sW[64 * wv + 16 * mb + col][off];
        acc[0][mb] = __builtin_amdgcn_mfma_f32_16x16x32_bf16(a0, wb, acc[0][mb], 0, 0, 0);
        acc[1][mb] = __builtin_amdgcn_mfma_f32_16x16x32_bf16(a1, wb, acc[1][mb], 0, 0, 0);
      }
    }
  }

  __syncthreads();   // all MFMA reads of sW done before tr alias-writes
#pragma unroll
  for (int nf = 0; nf < 2; nf++)
#pragma unroll
    for (int mb = 0; mb < 4; mb++) {
      const float bi = bias[64 * wv + 16 * mb + col];
#pragma unroll
      for (int r = 0; r < 4; r++)
        tr[16 * nf + 4 * quad + r][64 * wv + 16 * mb + col] = f2bf(acc[nf][mb][r] + bi);
    }
  __syncthreads();
  {  // store 32 rows x 512 B coalesced
    const int row = tid >> 3, seg = tid & 7;
    ushort* dst = &AT[((size_t)(which * BB + b) * NN + n0 + row) * HH];
#pragma unroll
    for (int j = 0; j < 4; j++)
      *(uint4*)&dst[(seg * 4 + j) * 8] = *(const uint4*)&tr[row][(seg * 4 + j) * 8];
  }
}

// ---------------------------------------------------------------------------
// attn+score per (which,b,k): num = sum exp(S)*G, den = sum exp(S);
// S = (wk.*Aa)^T Ac, G = (wfc_k.*Aa)^T Ac.  32x32x16 MFMA: C-layout is
// irrelevant (exp+reduce only), and any self-consistent [idx][k] operand
// mapping is numerically exact, so the 32x32 fragment layout cannot break
// correctness.  A-frags (both variants, K=256) packed ONCE per 32-row
// n-strip and held in regs (~128 VGPR); m swept in 64-row LDS chunks; each
// B-read feeds 2 MFMAs and B-bytes/FLOP are half of the 16x16 version.
// blockIdx = k*64+g keeps the 8 k-replicas of (which,b) on one XCD.
// ---------------------------------------------------------------------------
__global__ __launch_bounds__(256, 2) void attn_kernel(
    const ushort* __restrict__ AT, const float* __restrict__ Watt,
    const float* __restrict__ Wfc, float* __restrict__ scoresK)
{
  const int idx = blockIdx.x;
  const int k = idx >> 6;
  const int g = idx & 63;
  const int which = g >> 5;
  const int b = g & 31;
  const int tid = threadIdx.x;
  const int wv = tid >> 6;
  const int lane = tid & 63;
  const int row32 = lane & 31;
  const int half32 = lane >> 5;

  const ushort* At_a = AT + (size_t)b * NN * HH;                       // anchor [n][h]
  const ushort* At_c = AT + ((size_t)(1 + which) * BB + b) * NN * HH;  // pos/neg [m][h]
  const uint4* Ac_u4 = (const uint4*)At_c;

  __shared__ __align__(16) ushort sAc[64][264];   // [m_local][h]
  __shared__ __align__(16) float wkf[256];
  __shared__ __align__(16) float wff[256];
  __shared__ float red[8];

  wkf[tid] = Watt[(size_t)k * HH + tid];
  wff[tid] = Wfc[(size_t)k * HH + tid];
  __syncthreads();                                // wkf/wff visible to packs

  float num = 0.f, den = 0.f;
  const int srow = tid >> 5, scol8 = (tid & 31) * 8;

  for (int s = 0; s < 2; s++) {
    const int nbase = 128 * s + 32 * wv;          // wave's 32-row n-strip
    // ---- pack A-frags for both variants, full K=256 (held across m sweep)
    bf16x8 saf[16], gaf[16];
    const ushort* arow = At_a + (size_t)(nbase + row32) * HH;
#pragma unroll
    for (int ks = 0; ks < 16; ks++) {
      const int off = 16 * ks + 8 * half32;
      const bf16x8 a = *(const bf16x8*)&arow[off];          // global, L2-hot
      const float4 wa = *(const float4*)&wkf[off];
      const float4 wb = *(const float4*)&wkf[off + 4];
      const float4 fa = *(const float4*)&wff[off];
      const float4 fb = *(const float4*)&wff[off + 4];
      const float w[8] = {wa.x, wa.y, wa.z, wa.w, wb.x, wb.y, wb.z, wb.w};
      const float f[8] = {fa.x, fa.y, fa.z, fa.w, fb.x, fb.y, fb.z, fb.w};
      union { bf16x8 v; unsigned u[4]; } sv, gv;
#pragma unroll
      for (int jj = 0; jj < 4; jj++) {
        const float a0 = bf2f((ushort)a[2 * jj]), a1 = bf2f((ushort)a[2 * jj + 1]);
        sv.u[jj] = pack2bf(a0 * w[2 * jj], a1 * w[2 * jj + 1]);
        gv.u[jj] = pack2bf(a0 * f[2 * jj], a1 * f[2 * jj + 1]);
      }
      saf[ks] = sv.v; gaf[ks] = gv.v;
    }

    for (int mc = 0; mc < 4; mc++) {              // 64-row m-chunks
      __syncthreads();                            // prev chunk reads done
#pragma unroll
      for (int q = 0; q < 8; q++) {               // stage: 8 uint4/thread
        const int row = q * 8 + srow;
        *(uint4*)&sAc[row][scol8] = Ac_u4[(size_t)(64 * mc + row) * 32 + (tid & 31)];
      }
      __syncthreads();

      f32x16 aS0 = {0,0,0,0,0,0,0,0,0,0,0,0,0,0,0,0};
      f32x16 aS1 = {0,0,0,0,0,0,0,0,0,0,0,0,0,0,0,0};
      f32x16 aG0 = {0,0,0,0,0,0,0,0,0,0,0,0,0,0,0,0};
      f32x16 aG1 = {0,0,0,0,0,0,0,0,0,0,0,0,0,0,0,0};
#pragma unroll
      for (int ks = 0; ks < 16; ks++) {
        const int off = 16 * ks + 8 * half32;
        const bf16x8 b0 = *(const bf16x8*)&sAc[row32][off];
        const bf16x8 b1 = *(const bf16x8*)&sAc[32 + row32][off];
        aS0 = __builtin_amdgcn_mfma_f32_32x32x16_bf16(saf[ks], b0, aS0, 0, 0, 0);
        aG0 = __builtin_amdgcn_mfma_f32_32x32x16_bf16(gaf[ks], b0, aG0, 0, 0, 0);
        aS1 = __builtin_amdgcn_mfma_f32_32x32x16_bf16(saf[ks], b1, aS1, 0, 0, 0);
        aG1 = __builtin_amdgcn_mfma_f32_32x32x16_bf16(gaf[ks], b1, aG1, 0, 0, 0);
      }
#pragma unroll
      for (int r = 0; r < 16; r++) {
        const float p0 = __expf(aS0[r]);
        den += p0; num += p0 * aG0[r];
        const float p1 = __expf(aS1[r]);
        den += p1; num += p1 * aG1[r];
      }
    }
  }

  // reduce num/den: 64-lane butterfly, then 4 waves via LDS
#pragma unroll
  for (int off = 32; off >= 1; off >>= 1) {
    num += __shfl_xor(num, off);
    den += __shfl_xor(den, off);
  }
  if (lane == 0) { red[wv] = num; red[4 + wv] = den; }
  __syncthreads();
  if (tid == 0) {
    const float nt = red[0] + red[1] + red[2] + red[3];
    const float dt = red[4] + red[5] + red[6] + red[7];
    scoresK[idx] = nt / dt;
  }
}

// ---------------------------------------------------------------------------
// loss: score(g) = b_fc + sum_k scoresK[k*64+g]; mean_b relu(sn - sp + margin)
// ---------------------------------------------------------------------------
__global__ __launch_bounds__(64) void loss_kernel(
    const float* __restrict__ scoresK, const float* __restrict__ bfc,
    float* __restrict__ out)
{
  const int tid = threadIdx.x;    // tid = which*32 + b
  float s = bfc[0];
#pragma unroll
  for (int k = 0; k < KK; k++) s += scoresK[k * 64 + tid];
  const float other = __shfl(s, tid + 32);   // wraps mod 64; valid for tid<32
  float v = 0.f;
  if (tid < 32) v = fmaxf(other - s + MARGINF, 0.f);
#pragma unroll
  for (int off = 32; off >= 1; off >>= 1) v += __shfl_xor(v, off);
  if (tid == 0) out[0] = v * (1.0f / 32.0f);
}

// ---------------------------------------------------------------------------
extern "C" void kernel_launch(void* const* d_in, const int* in_sizes, int n_in,
                              void* d_out, int out_size, void* d_ws, size_t ws_size,
                              hipStream_t stream) {
  const float* he_a  = (const float*)d_in[0];
  const float* he_p  = (const float*)d_in[1];
  const float* he_n  = (const float*)d_in[2];
  const float* W_a2h = (const float*)d_in[3];
  const float* b_a2h = (const float*)d_in[4];
  const float* W_c2h = (const float*)d_in[5];
  const float* b_c2h = (const float*)d_in[6];
  const float* W_att = (const float*)d_in[7];
  // d_in[8] = b_att: cancels in global softmax
  const float* W_fc  = (const float*)d_in[9];
  const float* b_fc  = (const float*)d_in[10];

  ushort* AT = (ushort*)d_ws;                               // [3][B][N][H] bf16, 12.6 MB
  float* scoresK = (float*)(AT + (size_t)3 * BB * NN * HH); // [512] fp32
  (void)ws_size; (void)in_sizes; (void)n_in; (void)out_size;

  dim3 pg(8, 96);
  proj_kernel<<<pg, 256, 0, stream>>>(he_a, he_p, he_n, W_a2h, b_a2h, W_c2h, b_c2h, AT);
  attn_kernel<<<512, 256, 0, stream>>>(AT, W_att, W_fc, scoresK);
  loss_kernel<<<1, 64, 0, stream>>>(scoresK, b_fc, (float*)d_out);
}

// Round 7
// 147.985 us; speedup vs baseline: 10.6455x; 1.1000x over previous
//
#include <hip/hip_runtime.h>

#define BB 32
#define NN 256
#define EE 300
#define HH 256
#define KK 8
#define MARGINF 0.2f
#define EP 320   // E padded for K-loop

typedef __attribute__((ext_vector_type(8))) short bf16x8;
typedef __attribute__((ext_vector_type(4))) float f32x4;
typedef __attribute__((ext_vector_type(16))) float f32x16;

__device__ inline ushort f2bf(float f) {
  unsigned u = __float_as_uint(f);
  u += 0x7fffu + ((u >> 16) & 1u);          // RNE
  return (ushort)(u >> 16);
}
__device__ inline float bf2f(ushort s) { return __uint_as_float(((unsigned)s) << 16); }
__device__ inline unsigned pack2bf(float f0, float f1) {   // [f0 lo | f1 hi], RNE
  unsigned u0 = __float_as_uint(f0); u0 += 0x7fffu + ((u0 >> 16) & 1u);
  unsigned u1 = __float_as_uint(f1); u1 += 0x7fffu + ((u1 >> 16) & 1u);
  return (u0 >> 16) | (u1 & 0xffff0000u);
}

// ---------------------------------------------------------------------------
// wconv: W_a2h/W_c2h fp32 [256][300] -> Wb bf16 [2][256][320] (zero-padded).
// Pure streaming, ~320 KB out. Done ONCE so proj never touches fp32 W.
// ---------------------------------------------------------------------------
__global__ __launch_bounds__(256) void wconv_kernel(
    const float* __restrict__ Wa, const float* __restrict__ Wc,
    ushort* __restrict__ Wb)
{
  const int i = blockIdx.x * 256 + threadIdx.x;   // over 2*256*320 = 163840
  const int e = i % EP;
  const int hw = i / EP;
  const int h = hw & 255;
  const int w = hw >> 8;
  const float* src = w ? Wc : Wa;
  Wb[i] = (e < EE) ? f2bf(src[(size_t)h * EE + e]) : (ushort)0;
}

// ---------------------------------------------------------------------------
// proj v2: one WG per (which,b,32-row n-tile), full H=256 output.
// X tile (32x300 fp32) packed to LDS once -> ONE barrier; K-loop reads W
// B-fragments as 16B gathers straight from L2-hot bf16 Wb (no LDS, no
// chunk barriers -> loads from all waves pipeline freely).
// MFMA 16x16x32, operand/C layout identical to round-6-verified version.
// ---------------------------------------------------------------------------
__global__ __launch_bounds__(256, 3) void proj_kernel(
    const float* __restrict__ he_a, const float* __restrict__ he_p,
    const float* __restrict__ he_n, const ushort* __restrict__ Wb,
    const float* __restrict__ b_a2h, const float* __restrict__ b_c2h,
    ushort* __restrict__ AT)
{
  const int z = blockIdx.y;           // 96 = 3*BB
  const int which = z >> 5;
  const int b = z & 31;
  const int n0 = blockIdx.x * 32;
  const int tid = threadIdx.x;
  const int wv = tid >> 6;
  const int lane = tid & 63;
  const int col = lane & 15;
  const int quad = lane >> 4;

  const float* X = (which == 0 ? he_a : which == 1 ? he_p : he_n) + (size_t)b * NN * EE;
  const ushort* W = Wb + (size_t)(which == 0 ? 0 : 1) * HH * EP;
  const float* bias = (which == 0 ? b_a2h : b_c2h);

  __shared__ __align__(16) ushort sX[32][328];  // stride 164 dw (%32=4 -> 2-way, free)
  __shared__ __align__(16) ushort tr[32][264];

  // ---- stage X tile: 32 rows x 320 bf16 (zero-pad past 300); 8 thr/row
  {
    const int row = tid >> 3, seg = tid & 7;
    const float* xr = X + (size_t)(n0 + row) * EE;
#pragma unroll
    for (int q = 0; q < 10; q++) {
      const int j = seg + 8 * q;           // float4 slot 0..79 (75 valid)
      float4 xv = {0.f, 0.f, 0.f, 0.f};
      if (j < 75) xv = *(const float4*)&xr[4 * j];
      uint2 p; p.x = pack2bf(xv.x, xv.y); p.y = pack2bf(xv.z, xv.w);
      *(uint2*)&sX[row][4 * j] = p;
    }
  }
  __syncthreads();

  f32x4 acc[2][4];
#pragma unroll
  for (int nf = 0; nf < 2; nf++)
#pragma unroll
    for (int mb = 0; mb < 4; mb++) acc[nf][mb] = (f32x4){0.f, 0.f, 0.f, 0.f};

#pragma unroll
  for (int ks = 0; ks < 10; ks++) {
    const int off = 32 * ks + 8 * quad;
    const bf16x8 a0 = *(const bf16x8*)&sX[col][off];
    const bf16x8 a1 = *(const bf16x8*)&sX[16 + col][off];
#pragma unroll
    for (int mb = 0; mb < 4; mb++) {
      const bf16x8 w8 = *(const bf16x8*)&W[(size_t)(64 * wv + 16 * mb + col) * EP + off];
      acc[0][mb] = __builtin_amdgcn_mfma_f32_16x16x32_bf16(a0, w8, acc[0][mb], 0, 0, 0);
      acc[1][mb] = __builtin_amdgcn_mfma_f32_16x16x32_bf16(a1, w8, acc[1][mb], 0, 0, 0);
    }
  }

  // ---- epilogue: +bias, bf16, transpose through LDS, coalesced store
#pragma unroll
  for (int nf = 0; nf < 2; nf++)
#pragma unroll
    for (int mb = 0; mb < 4; mb++) {
      const float bi = bias[64 * wv + 16 * mb + col];
#pragma unroll
      for (int r = 0; r < 4; r++)
        tr[16 * nf + 4 * quad + r][64 * wv + 16 * mb + col] = f2bf(acc[nf][mb][r] + bi);
    }
  __syncthreads();
  {
    const int row = tid >> 3, seg = tid & 7;
    ushort* dst = &AT[((size_t)(which * BB + b) * NN + n0 + row) * HH];
#pragma unroll
    for (int j = 0; j < 4; j++)
      *(uint4*)&dst[(seg * 4 + j) * 8] = *(const uint4*)&tr[row][(seg * 4 + j) * 8];
  }
}

// ---------------------------------------------------------------------------
// attn+score per (which,b,k) — unchanged from round 6 (32x32x16 MFMA,
// A-frags packed once per n-strip, B reads from LDS feed 2 MFMAs each).
// ---------------------------------------------------------------------------
__global__ __launch_bounds__(256, 2) void attn_kernel(
    const ushort* __restrict__ AT, const float* __restrict__ Watt,
    const float* __restrict__ Wfc, float* __restrict__ scoresK)
{
  const int idx = blockIdx.x;
  const int k = idx >> 6;
  const int g = idx & 63;
  const int which = g >> 5;
  const int b = g & 31;
  const int tid = threadIdx.x;
  const int wv = tid >> 6;
  const int lane = tid & 63;
  const int row32 = lane & 31;
  const int half32 = lane >> 5;

  const ushort* At_a = AT + (size_t)b * NN * HH;                       // anchor [n][h]
  const ushort* At_c = AT + ((size_t)(1 + which) * BB + b) * NN * HH;  // pos/neg [m][h]
  const uint4* Ac_u4 = (const uint4*)At_c;

  __shared__ __align__(16) ushort sAc[64][264];   // [m_local][h]
  __shared__ __align__(16) float wkf[256];
  __shared__ __align__(16) float wff[256];
  __shared__ float red[8];

  wkf[tid] = Watt[(size_t)k * HH + tid];
  wff[tid] = Wfc[(size_t)k * HH + tid];
  __syncthreads();

  float num = 0.f, den = 0.f;
  const int srow = tid >> 5, scol8 = (tid & 31) * 8;

  for (int s = 0; s < 2; s++) {
    const int nbase = 128 * s + 32 * wv;
    bf16x8 saf[16], gaf[16];
    const ushort* arow = At_a + (size_t)(nbase + row32) * HH;
#pragma unroll
    for (int ks = 0; ks < 16; ks++) {
      const int off = 16 * ks + 8 * half32;
      const bf16x8 a = *(const bf16x8*)&arow[off];          // global, L2-hot
      const float4 wa = *(const float4*)&wkf[off];
      const float4 wb = *(const float4*)&wkf[off + 4];
      const float4 fa = *(const float4*)&wff[off];
      const float4 fb = *(const float4*)&wff[off + 4];
      const float w[8] = {wa.x, wa.y, wa.z, wa.w, wb.x, wb.y, wb.z, wb.w};
      const float f[8] = {fa.x, fa.y, fa.z, fa.w, fb.x, fb.y, fb.z, fb.w};
      union { bf16x8 v; unsigned u[4]; } sv, gv;
#pragma unroll
      for (int jj = 0; jj < 4; jj++) {
        const float a0 = bf2f((ushort)a[2 * jj]), a1 = bf2f((ushort)a[2 * jj + 1]);
        sv.u[jj] = pack2bf(a0 * w[2 * jj], a1 * w[2 * jj + 1]);
        gv.u[jj] = pack2bf(a0 * f[2 * jj], a1 * f[2 * jj + 1]);
      }
      saf[ks] = sv.v; gaf[ks] = gv.v;
    }

    for (int mc = 0; mc < 4; mc++) {
      __syncthreads();
#pragma unroll
      for (int q = 0; q < 8; q++) {
        const int row = q * 8 + srow;
        *(uint4*)&sAc[row][scol8] = Ac_u4[(size_t)(64 * mc + row) * 32 + (tid & 31)];
      }
      __syncthreads();

      f32x16 aS0 = {0,0,0,0,0,0,0,0,0,0,0,0,0,0,0,0};
      f32x16 aS1 = {0,0,0,0,0,0,0,0,0,0,0,0,0,0,0,0};
      f32x16 aG0 = {0,0,0,0,0,0,0,0,0,0,0,0,0,0,0,0};
      f32x16 aG1 = {0,0,0,0,0,0,0,0,0,0,0,0,0,0,0,0};
#pragma unroll
      for (int ks = 0; ks < 16; ks++) {
        const int off = 16 * ks + 8 * half32;
        const bf16x8 b0 = *(const bf16x8*)&sAc[row32][off];
        const bf16x8 b1 = *(const bf16x8*)&sAc[32 + row32][off];
        aS0 = __builtin_amdgcn_mfma_f32_32x32x16_bf16(saf[ks], b0, aS0, 0, 0, 0);
        aG0 = __builtin_amdgcn_mfma_f32_32x32x16_bf16(gaf[ks], b0, aG0, 0, 0, 0);
        aS1 = __builtin_amdgcn_mfma_f32_32x32x16_bf16(saf[ks], b1, aS1, 0, 0, 0);
        aG1 = __builtin_amdgcn_mfma_f32_32x32x16_bf16(gaf[ks], b1, aG1, 0, 0, 0);
      }
#pragma unroll
      for (int r = 0; r < 16; r++) {
        const float p0 = __expf(aS0[r]);
        den += p0; num += p0 * aG0[r];
        const float p1 = __expf(aS1[r]);
        den += p1; num += p1 * aG1[r];
      }
    }
  }

#pragma unroll
  for (int off = 32; off >= 1; off >>= 1) {
    num += __shfl_xor(num, off);
    den += __shfl_xor(den, off);
  }
  if (lane == 0) { red[wv] = num; red[4 + wv] = den; }
  __syncthreads();
  if (tid == 0) {
    const float nt = red[0] + red[1] + red[2] + red[3];
    const float dt = red[4] + red[5] + red[6] + red[7];
    scoresK[idx] = nt / dt;
  }
}

// ---------------------------------------------------------------------------
__global__ __launch_bounds__(64) void loss_kernel(
    const float* __restrict__ scoresK, const float* __restrict__ bfc,
    float* __restrict__ out)
{
  const int tid = threadIdx.x;    // tid = which*32 + b
  float s = bfc[0];
#pragma unroll
  for (int k = 0; k < KK; k++) s += scoresK[k * 64 + tid];
  const float other = __shfl(s, tid + 32);
  float v = 0.f;
  if (tid < 32) v = fmaxf(other - s + MARGINF, 0.f);
#pragma unroll
  for (int off = 32; off >= 1; off >>= 1) v += __shfl_xor(v, off);
  if (tid == 0) out[0] = v * (1.0f / 32.0f);
}

// ---------------------------------------------------------------------------
extern "C" void kernel_launch(void* const* d_in, const int* in_sizes, int n_in,
                              void* d_out, int out_size, void* d_ws, size_t ws_size,
                              hipStream_t stream) {
  const float* he_a  = (const float*)d_in[0];
  const float* he_p  = (const float*)d_in[1];
  const float* he_n  = (const float*)d_in[2];
  const float* W_a2h = (const float*)d_in[3];
  const float* b_a2h = (const float*)d_in[4];
  const float* W_c2h = (const float*)d_in[5];
  const float* b_c2h = (const float*)d_in[6];
  const float* W_att = (const float*)d_in[7];
  // d_in[8] = b_att: cancels in global softmax
  const float* W_fc  = (const float*)d_in[9];
  const float* b_fc  = (const float*)d_in[10];

  ushort* AT = (ushort*)d_ws;                                // [3][B][N][H] bf16, 12.6 MB
  float* scoresK = (float*)(AT + (size_t)3 * BB * NN * HH);  // [512] fp32
  ushort* Wb = (ushort*)(scoresK + 512);                     // [2][256][320] bf16, 320 KB
  (void)ws_size; (void)in_sizes; (void)n_in; (void)out_size;

  wconv_kernel<<<640, 256, 0, stream>>>(W_a2h, W_c2h, Wb);
  dim3 pg(8, 96);
  proj_kernel<<<pg, 256, 0, stream>>>(he_a, he_p, he_n, Wb, b_a2h, b_c2h, AT);
  attn_kernel<<<512, 256, 0, stream>>>(AT, W_att, W_fc, scoresK);
  loss_kernel<<<1, 64, 0, stream>>>(scoresK, b_fc, (float*)d_out);
}